// Round 6
// baseline (263.812 us; speedup 1.0000x reference)
//
#include <hip/hip_runtime.h>
#include <stdint.h>

#define DIM 256
#define NROWS 8192
#define KTOT 8192

typedef unsigned short u16;
typedef short bf16x8 __attribute__((ext_vector_type(8)));
typedef float f32x4 __attribute__((ext_vector_type(4)));

__device__ __forceinline__ u16 f2bf(float x) {
  uint32_t u = __float_as_uint(x);
  u = (u + 0x7FFFu + ((u >> 16) & 1u)) >> 16;
  return (u16)u;
}

__device__ __forceinline__ float wsum(float v) {
  v += __shfl_xor(v, 32, 64);
  v += __shfl_xor(v, 16, 64);
  v += __shfl_xor(v, 8, 64);
  v += __shfl_xor(v, 4, 64);
  v += __shfl_xor(v, 2, 64);
  v += __shfl_xor(v, 1, 64);
  return v;
}

__device__ __forceinline__ float artanh_c(float x) {
  const float lim = 1.0f - 1e-7f;
  x = fminf(fmaxf(x, -lim), lim);
  return 0.5f * (log1pf(x) - log1pf(-x));
}

// ---------------- K1: mx = x @ W^T  (fp32, 64x64 tiles) ----------------
__global__ __launch_bounds__(256)
void hgcn_k1(const float* __restrict__ x, const float* __restrict__ w,
             float* __restrict__ mx) {
  __shared__ float xs_t[32][64];
  __shared__ float ws_t[32][64];
  int t = threadIdx.x;
  int tx = t & 15, ty = t >> 4;
  int bi = blockIdx.x, bj = blockIdx.y;
  int lr = t >> 2, lc = (t & 3) * 8;
  const float* xp = x + (size_t)(bi * 64 + lr) * DIM + lc;
  const float* wp = w + (size_t)(bj * 64 + lr) * DIM + lc;
  float acc[4][4] = {};
  for (int kb = 0; kb < DIM; kb += 32) {
    float4 a0 = *(const float4*)(xp + kb);
    float4 a1 = *(const float4*)(xp + kb + 4);
    float4 b0 = *(const float4*)(wp + kb);
    float4 b1 = *(const float4*)(wp + kb + 4);
    __syncthreads();
    xs_t[lc + 0][lr] = a0.x; xs_t[lc + 1][lr] = a0.y;
    xs_t[lc + 2][lr] = a0.z; xs_t[lc + 3][lr] = a0.w;
    xs_t[lc + 4][lr] = a1.x; xs_t[lc + 5][lr] = a1.y;
    xs_t[lc + 6][lr] = a1.z; xs_t[lc + 7][lr] = a1.w;
    ws_t[lc + 0][lr] = b0.x; ws_t[lc + 1][lr] = b0.y;
    ws_t[lc + 2][lr] = b0.z; ws_t[lc + 3][lr] = b0.w;
    ws_t[lc + 4][lr] = b1.x; ws_t[lc + 5][lr] = b1.y;
    ws_t[lc + 6][lr] = b1.z; ws_t[lc + 7][lr] = b1.w;
    __syncthreads();
#pragma unroll
    for (int k = 0; k < 32; ++k) {
      float4 xv = *(const float4*)&xs_t[k][ty * 4];
      float4 wv = *(const float4*)&ws_t[k][tx * 4];
      float xr[4] = {xv.x, xv.y, xv.z, xv.w};
      float wr[4] = {wv.x, wv.y, wv.z, wv.w};
#pragma unroll
      for (int ii = 0; ii < 4; ++ii)
#pragma unroll
        for (int jj = 0; jj < 4; ++jj)
          acc[ii][jj] += xr[ii] * wr[jj];
    }
  }
#pragma unroll
  for (int ii = 0; ii < 4; ++ii) {
    float4 o = {acc[ii][0], acc[ii][1], acc[ii][2], acc[ii][3]};
    *(float4*)(mx + (size_t)(bi * 64 + ty * 4 + ii) * DIM + bj * 64 + tx * 4) = o;
  }
}

// ------- K2: hyperbolic chain #1, emits x_tangent^T as bf16 [256][8192] -------
__global__ __launch_bounds__(256)
void hgcn_k2(const float* __restrict__ x, const float* __restrict__ mx,
             const float* __restrict__ bias, u16* __restrict__ xtT) {
  __shared__ u16 xl[64][256];
  const float maxn = 1.0f - 1e-5f;
  int t = threadIdx.x;
  int wave = t >> 6, lane = t & 63;
  int c0 = lane * 4;

  float4 b4 = *(const float4*)(bias + c0);
  float bn2 = wsum(b4.x * b4.x + b4.y * b4.y + b4.z * b4.z + b4.w * b4.w);
  float bn = fmaxf(sqrtf(bn2), 1e-15f);
  float sb = tanhf(bn) / bn;
  float hbx = b4.x * sb, hby = b4.y * sb, hbz = b4.z * sb, hbw = b4.w * sb;
  float ebn2 = wsum(hbx * hbx + hby * hby + hbz * hbz + hbw * hbw);
  float ebn = fmaxf(sqrtf(ebn2), 1e-15f);
  float sp = ebn > maxn ? maxn / ebn : 1.0f;
  hbx *= sp; hby *= sp; hbz *= sp; hbw *= sp;
  float y2 = (ebn * sp) * (ebn * sp);

  for (int rr = 0; rr < 16; ++rr) {
    int iloc = wave * 16 + rr;
    size_t row = (size_t)blockIdx.x * 64 + iloc;
    float4 xv = *(const float4*)(x + row * DIM + c0);
    float4 mv = *(const float4*)(mx + row * DIM + c0);
    float xn2 = wsum(xv.x * xv.x + xv.y * xv.y + xv.z * xv.z + xv.w * xv.w);
    float mxn2 = wsum(mv.x * mv.x + mv.y * mv.y + mv.z * mv.z + mv.w * mv.w);
    int zloc = (mv.x == 0.0f) && (mv.y == 0.0f) && (mv.z == 0.0f) && (mv.w == 0.0f);
    int zrow = __all(zloc);
    float xn = fmaxf(sqrtf(xn2), 1e-15f);
    float mxn = fmaxf(sqrtf(mxn2), 1e-15f);
    float rfac = tanhf(mxn / xn * artanh_c(xn)) / mxn;
    if (zrow) rfac = 0.0f;
    float hx = mv.x * rfac, hy = mv.y * rfac, hz = mv.z * rfac, hw = mv.w * rfac;
    float hn = fmaxf(fabsf(rfac) * mxn, 1e-15f);
    float s1 = hn > maxn ? maxn / hn : 1.0f;
    hx *= s1; hy *= s1; hz *= s1; hw *= s1;
    float x2 = (hn * s1) * (hn * s1);
    float xy = wsum(hx * hbx + hy * hby + hz * hbz + hw * hbw);
    float ca = 1.0f + 2.0f * xy + y2;
    float cb = 1.0f - x2;
    float den = 1.0f + 2.0f * xy + x2 * y2;
    float inv = 1.0f / fmaxf(den, 1e-15f);
    float ox = (ca * hx + cb * hbx) * inv;
    float oy = (ca * hy + cb * hby) * inv;
    float oz = (ca * hz + cb * hbz) * inv;
    float ow = (ca * hw + cb * hbw) * inv;
    float on2 = wsum(ox * ox + oy * oy + oz * oz + ow * ow);
    float on = fmaxf(sqrtf(on2), 1e-15f);
    float s2 = on > maxn ? maxn / on : 1.0f;
    ox *= s2; oy *= s2; oz *= s2; ow *= s2;
    float pn = fmaxf(on * s2, 1e-15f);
    float lf = artanh_c(pn) / pn;
    u16 tmp[4] = {f2bf(ox * lf), f2bf(oy * lf), f2bf(oz * lf), f2bf(ow * lf)};
    *(uint2*)&xl[iloc][c0] = *(const uint2*)tmp;
  }
  __syncthreads();
  int c = t;
  size_t ob = (size_t)c * KTOT + (size_t)blockIdx.x * 64;
  for (int ch = 0; ch < 8; ++ch) {
    u16 tmp[8];
#pragma unroll
    for (int q = 0; q < 8; ++q) tmp[q] = xl[ch * 8 + q][c];
    *(uint4*)(xtT + ob + ch * 8) = *(const uint4*)tmp;
  }
}

// ------- K3: support^T = xtT (bf16) x adj (fp32->bf16 in-reg), NO LDS, NO barriers -------
// Per wave: 64n x 64m output tile. Fragments loaded straight from global:
//   A (xtT, n-major k-contig): L2-resident 512KB slice per XCD (split-K=8 + XCD map)
//   B (adj rows, k-contig fp32): streamed once from HBM, cvt_pk_bf16 in-reg
// Latency hidden by TLP (4 blocks/CU target), not by barrier-coupled pipelining.
__global__ __launch_bounds__(256, 4)
void hgcn_k3(const float* __restrict__ adj, const u16* __restrict__ xtT,
             float* __restrict__ pbase, int xps_log, int ksize) {
  int t = threadIdx.x;
  int wave = t >> 6, lane = t & 63;
  int l15 = lane & 15, l4 = lane >> 4;
  int wm = wave >> 1, wn = wave & 1;       // 2m x 2n waves per block
  int bid = blockIdx.x;
  int xps_m1 = (1 << xps_log) - 1;
  int split = (bid & 7) >> xps_log;        // XCD-aligned k-split
  int sub = (bid & 7) & xps_m1;
  int tt = ((bid >> 3) << xps_log) + sub;  // 0..127: {m_tile, nb}
  int m_tile = tt >> 1, nb = tt & 1;
  int m0 = m_tile * 128 + wm * 64;
  int n0 = nb * 128 + wn * 64;
  int kbase = split * ksize;
  float* outp = pbase + (size_t)split * ((size_t)NROWS * DIM);

  // per-lane fragment base pointers (constant-indexed arrays -> registers)
  const u16* ap[4];
  const float* bp[4];
#pragma unroll
  for (int ni = 0; ni < 4; ++ni)
    ap[ni] = xtT + (size_t)(n0 + ni * 16 + l15) * KTOT + kbase + l4 * 8;
#pragma unroll
  for (int mi = 0; mi < 4; ++mi)
    bp[mi] = adj + (size_t)(m0 + mi * 16 + l15) * KTOT + kbase + l4 * 8;

  f32x4 acc[4][4];
#pragma unroll
  for (int i = 0; i < 4; ++i)
#pragma unroll
    for (int j = 0; j < 4; ++j)
      acc[i][j] = (f32x4){0.f, 0.f, 0.f, 0.f};

#pragma unroll 2
  for (int kk = 0; kk < ksize; kk += 32) {
    bf16x8 a[4], b[4];
#pragma unroll
    for (int ni = 0; ni < 4; ++ni)
      a[ni] = *(const bf16x8*)(ap[ni] + kk);
#pragma unroll
    for (int mi = 0; mi < 4; ++mi) {
      const float* p = bp[mi] + kk;
      float4 f0 = ((const float4*)p)[0];
      float4 f1 = ((const float4*)p)[1];
      uint32_t w0, w1, w2, w3;
      asm("v_cvt_pk_bf16_f32 %0, %1, %2" : "=v"(w0) : "v"(f0.x), "v"(f0.y));
      asm("v_cvt_pk_bf16_f32 %0, %1, %2" : "=v"(w1) : "v"(f0.z), "v"(f0.w));
      asm("v_cvt_pk_bf16_f32 %0, %1, %2" : "=v"(w2) : "v"(f1.x), "v"(f1.y));
      asm("v_cvt_pk_bf16_f32 %0, %1, %2" : "=v"(w3) : "v"(f1.z), "v"(f1.w));
      union { uint32_t u[4]; bf16x8 v; } cv;
      cv.u[0] = w0; cv.u[1] = w1; cv.u[2] = w2; cv.u[3] = w3;
      b[mi] = cv.v;
    }
#pragma unroll
    for (int ni = 0; ni < 4; ++ni)
#pragma unroll
      for (int mi = 0; mi < 4; ++mi)
        acc[ni][mi] = __builtin_amdgcn_mfma_f32_16x16x32_bf16(a[ni], b[mi], acc[ni][mi], 0, 0, 0);
  }

  // epilogue: D[n][m] -> partial[m][n]  (same verified mapping as r5)
#pragma unroll
  for (int ni = 0; ni < 4; ++ni)
#pragma unroll
    for (int mi = 0; mi < 4; ++mi) {
      int n = n0 + ni * 16 + l4 * 4;
      int m = m0 + mi * 16 + l15;
      *(f32x4*)(outp + (size_t)m * DIM + n) = acc[ni][mi];
    }
}

// ---------------- K4: sum nsplit partials + hyperbolic chain #2 -> d_out ----------------
__global__ __launch_bounds__(256)
void hgcn_k4(const float* __restrict__ pbase, size_t pstride, int nsplit,
             float* __restrict__ out) {
  const float maxn = 1.0f - 1e-5f;
  int t = threadIdx.x;
  int wave = t >> 6, lane = t & 63;
  size_t row = (size_t)blockIdx.x * 4 + wave;
  int c0 = lane * 4;
  size_t off = row * DIM + c0;
  float sx = 0.f, sy = 0.f, sz = 0.f, sw = 0.f;
  for (int i = 0; i < nsplit; ++i) {
    float4 v = *(const float4*)(pbase + (size_t)i * pstride + off);
    sx += v.x; sy += v.y; sz += v.z; sw += v.w;
  }
  float un2 = wsum(sx * sx + sy * sy + sz * sz + sw * sw);
  float un = fmaxf(sqrtf(un2), 1e-15f);
  float t1 = tanhf(un) / un;
  float hx = sx * t1, hy = sy * t1, hz = sz * t1, hw = sw * t1;
  float hn = fmaxf(fabsf(t1) * un, 1e-15f);
  float s1 = hn > maxn ? maxn / hn : 1.0f;
  hx *= s1; hy *= s1; hz *= s1; hw *= s1;
  float pn = fmaxf(hn * s1, 1e-15f);
  float lf = artanh_c(pn) / pn;
  float rx = fmaxf(hx * lf, 0.0f), ry = fmaxf(hy * lf, 0.0f);
  float rz = fmaxf(hz * lf, 0.0f), rw = fmaxf(hw * lf, 0.0f);
  float rn2 = wsum(rx * rx + ry * ry + rz * rz + rw * rw);
  float rn = fmaxf(sqrtf(rn2), 1e-15f);
  float t2 = tanhf(rn) / rn;
  float ox = rx * t2, oy = ry * t2, oz = rz * t2, ow = rw * t2;
  float on = fmaxf(fabsf(t2) * rn, 1e-15f);
  float s3 = on > maxn ? maxn / on : 1.0f;
  float4 o = {ox * s3, oy * s3, oz * s3, ow * s3};
  *(float4*)(out + off) = o;
}

extern "C" void kernel_launch(void* const* d_in, const int* in_sizes, int n_in,
                              void* d_out, int out_size, void* d_ws, size_t ws_size,
                              hipStream_t stream) {
  const float* x = (const float*)d_in[0];
  const float* adj = (const float*)d_in[1];
  const float* wgt = (const float*)d_in[2];
  const float* bias = (const float*)d_in[3];
  float* out = (float*)d_out;
  char* ws = (char*)d_ws;
  float* mx = (float*)ws;                      // [0, 8MB)
  u16* xtT = (u16*)(ws + (8u << 20));          // [8MB, 12MB)
  float* pbase = (float*)(ws + (12u << 20));   // [12MB, 12MB + ksplit*8MB)

  const size_t PBYTES = (size_t)NROWS * DIM * 4;   // 8MB per partial
  const size_t BASE = (size_t)12 << 20;
  int ksplit = (ws_size >= BASE + 8 * PBYTES) ? 8
             : (ws_size >= BASE + 4 * PBYTES) ? 4 : 2;
  int xps_log = (ksplit == 8) ? 0 : (ksplit == 4) ? 1 : 2;
  int ksize = KTOT / ksplit;

  hipLaunchKernelGGL(hgcn_k1, dim3(128, 4), dim3(256), 0, stream, x, wgt, mx);
  hipLaunchKernelGGL(hgcn_k2, dim3(128), dim3(256), 0, stream, x, mx, bias, xtT);
  hipLaunchKernelGGL(hgcn_k3, dim3(128 * ksplit), dim3(256), 0, stream,
                     adj, xtT, pbase, xps_log, ksize);
  hipLaunchKernelGGL(hgcn_k4, dim3(2048), dim3(256), 0, stream,
                     pbase, (size_t)NROWS * DIM, ksplit, out);
}